// Round 6
// baseline (542.108 us; speedup 1.0000x reference)
//
#include <hip/hip_runtime.h>
#include <hip/hip_bf16.h>
#include <stdint.h>

typedef short short8 __attribute__((ext_vector_type(8)));
typedef float f32x4 __attribute__((ext_vector_type(4)));

// ---------- helpers ----------
__device__ __forceinline__ unsigned short f2bf(float x) {
    unsigned u = __float_as_uint(x);
    u += 0x7fffu + ((u >> 16) & 1u);   // RNE
    return (unsigned short)(u >> 16);
}
__device__ __forceinline__ float bflo(unsigned u) { return __uint_as_float(u << 16); }
__device__ __forceinline__ float bfhi(unsigned u) { return __uint_as_float(u & 0xffff0000u); }

// ---------- weight prep (+ degree count, fused) ----------
// W [K][128] f32 -> Wt [128][ldd] bf16 at koff; perm=1 applies paired-row permutation
struct WDesc { const float* src; unsigned short* dst; int K, ldd, koff, perm; };
struct WPack { WDesc w[12]; };

__global__ __launch_bounds__(256) void prep_and_count(WPack p,
        const int* __restrict__ d0, int E0, int* c0,
        const int* __restrict__ d1, int E1, int* c1, int nPrep) {
    if ((int)blockIdx.x < nPrep) {
        int wi = blockIdx.x >> 2, chunk = blockIdx.x & 3;
        WDesc d = p.w[wi];
        int total = d.K * 128, cs = total >> 2;
        int lo = chunk * cs, hi = lo + cs;
        for (int i = lo + threadIdx.x; i < hi; i += 256) {
            int n = i / d.K, k = i - n * d.K;
            int kk = d.perm ? (2 * (k & 63) + (k >> 6)) : k;
            d.dst[(size_t)n * d.ldd + d.koff + kk] = f2bf(d.src[(size_t)k * 128 + n]);
        }
    } else {
        int t = (blockIdx.x - nPrep) * 256 + threadIdx.x;
        if (t < E0) atomicAdd(&c0[d0[t]], 1);
        else if (t < E0 + E1) atomicAdd(&c1[d1[t - E0]], 1);
    }
}

// ========== merged node+edge projections: one launch, fully barrier/LDS-free ======
// Every wave owns a private 32-row tile; A-fragments AND B-fragments are loaded
// directly from global (weights are L2-resident). Edge blocks (memory-latency
// bound) and node blocks (MFMA bound) co-reside on CUs and overlap.
struct ProjDesc { const unsigned short* Wt; const float* bias; unsigned int* out; int ldc, coloff; };
struct NodeJob { const float* A; int M; int nout; ProjDesc d[5]; };
struct EdgeJob {
    const float* A; const unsigned short* Wt; const float* bias;
    const int* pos; unsigned int* out; int M;
};

__global__ __launch_bounds__(256) void gemm_ne(EdgeJob e0, EdgeJob e1, NodeJob n0, NodeJob n1,
                                               int BE0, int BE1, int BN0) {
    const int tid = threadIdx.x;
    const int lane = tid & 63, w = tid >> 6;
    const int qd = lane >> 4, l16 = lane & 15;
    int b = blockIdx.x;

    if (b < BE0 + BE1) {
        // ---------------- edge path: K=64, scatter to CSR position ----------------
        EdgeJob p; int blk;
        if (b < BE0) { p = e0; blk = b; } else { p = e1; blk = b - BE0; }
        const int rbase = blk * 128 + w * 32;
        if (rbase >= p.M) return;

        short8 af[2][2];
#pragma unroll
        for (int rt = 0; rt < 2; ++rt)
#pragma unroll
            for (int ks = 0; ks < 2; ++ks) {
                int gr = rbase + rt * 16 + l16;
                int grc = gr < p.M ? gr : p.M - 1;   // clamp: finite, stores guarded
                const float* a = p.A + (size_t)grc * 64 + ks * 32 + qd * 8;
                float4 f0 = *reinterpret_cast<const float4*>(a);
                float4 f1 = *reinterpret_cast<const float4*>(a + 4);
                short8 s;
                s[0] = (short)f2bf(f0.x); s[1] = (short)f2bf(f0.y);
                s[2] = (short)f2bf(f0.z); s[3] = (short)f2bf(f0.w);
                s[4] = (short)f2bf(f1.x); s[5] = (short)f2bf(f1.y);
                s[6] = (short)f2bf(f1.z); s[7] = (short)f2bf(f1.w);
                af[rt][ks] = s;
            }

        f32x4 acc[2][8];
#pragma unroll
        for (int rt = 0; rt < 2; ++rt)
#pragma unroll
            for (int ct = 0; ct < 8; ++ct) { f32x4 z = {0.f,0.f,0.f,0.f}; acc[rt][ct] = z; }
#pragma unroll
        for (int ks = 0; ks < 2; ++ks)
#pragma unroll
            for (int ct = 0; ct < 8; ++ct) {
                short8 bf = *reinterpret_cast<const short8*>(
                    p.Wt + (size_t)(ct * 16 + l16) * 64 + ks * 32 + qd * 8);
                acc[0][ct] = __builtin_amdgcn_mfma_f32_16x16x32_bf16(af[0][ks], bf, acc[0][ct], 0, 0, 0);
                acc[1][ct] = __builtin_amdgcn_mfma_f32_16x16x32_bf16(af[1][ks], bf, acc[1][ct], 0, 0, 0);
            }

        float blo[4], bhi[4];
#pragma unroll
        for (int ct = 0; ct < 4; ++ct) {
            blo[ct] = p.bias[ct * 16 + l16];
            bhi[ct] = p.bias[64 + ct * 16 + l16];
        }
#pragma unroll
        for (int rt = 0; rt < 2; ++rt)
#pragma unroll
            for (int r = 0; r < 4; ++r) {
                int gr = rbase + rt * 16 + qd * 4 + r;
                if (gr < p.M) {
                    int dpos = p.pos[gr];
                    unsigned int* dst = p.out + (size_t)dpos * 64 + l16;
#pragma unroll
                    for (int ct = 0; ct < 4; ++ct) {
                        unsigned lo = f2bf(acc[rt][ct][r] + blo[ct]);
                        unsigned hi = f2bf(acc[rt][ct + 4][r] + bhi[ct]);
                        dst[ct * 16] = lo | (hi << 16);
                    }
                }
            }
    } else {
        // ---------------- node path: K=128, up to 5 projections ----------------
        NodeJob p; int blk;
        int bb = b - BE0 - BE1;
        if (bb < BN0) { p = n0; blk = bb; } else { p = n1; blk = bb - BN0; }
        const int rbase = blk * 128 + w * 32;
        if (rbase >= p.M) return;

        short8 af[2][4];
#pragma unroll
        for (int rt = 0; rt < 2; ++rt)
#pragma unroll
            for (int ks = 0; ks < 4; ++ks) {
                int gr = rbase + rt * 16 + l16;
                int grc = gr < p.M ? gr : p.M - 1;
                const float* a = p.A + (size_t)grc * 128 + ks * 32 + qd * 8;
                float4 f0 = *reinterpret_cast<const float4*>(a);
                float4 f1 = *reinterpret_cast<const float4*>(a + 4);
                short8 s;
                s[0] = (short)f2bf(f0.x); s[1] = (short)f2bf(f0.y);
                s[2] = (short)f2bf(f0.z); s[3] = (short)f2bf(f0.w);
                s[4] = (short)f2bf(f1.x); s[5] = (short)f2bf(f1.y);
                s[6] = (short)f2bf(f1.z); s[7] = (short)f2bf(f1.w);
                af[rt][ks] = s;
            }

        for (int o = 0; o < p.nout; ++o) {
            ProjDesc d = p.d[o];
            f32x4 acc[2][8];
#pragma unroll
            for (int rt = 0; rt < 2; ++rt)
#pragma unroll
                for (int ct = 0; ct < 8; ++ct) { f32x4 z = {0.f,0.f,0.f,0.f}; acc[rt][ct] = z; }
#pragma unroll
            for (int ks = 0; ks < 4; ++ks)
#pragma unroll
                for (int ct = 0; ct < 8; ++ct) {
                    short8 bf = *reinterpret_cast<const short8*>(
                        d.Wt + (size_t)(ct * 16 + l16) * 128 + ks * 32 + qd * 8);
                    acc[0][ct] = __builtin_amdgcn_mfma_f32_16x16x32_bf16(af[0][ks], bf, acc[0][ct], 0, 0, 0);
                    acc[1][ct] = __builtin_amdgcn_mfma_f32_16x16x32_bf16(af[1][ks], bf, acc[1][ct], 0, 0, 0);
                }

            float blo[4], bhi[4];
#pragma unroll
            for (int ct = 0; ct < 4; ++ct) {
                blo[ct] = d.bias[ct * 16 + l16];
                bhi[ct] = d.bias[64 + ct * 16 + l16];
            }
#pragma unroll
            for (int rt = 0; rt < 2; ++rt)
#pragma unroll
                for (int r = 0; r < 4; ++r) {
                    int gr = rbase + rt * 16 + qd * 4 + r;
                    if (gr < p.M) {
                        unsigned int* dst = d.out + (size_t)gr * d.ldc + d.coloff + l16;
#pragma unroll
                        for (int ct = 0; ct < 4; ++ct) {
                            unsigned lo = f2bf(acc[rt][ct][r] + blo[ct]);
                            unsigned hi = f2bf(acc[rt][ct + 4][r] + bhi[ct]);
                            dst[ct * 16] = lo | (hi << 16);
                        }
                    }
                }
        }
    }
}

// ===== output GEMM: out = LN( [agg|x] @ [Wo;Wnp] + bo + bnp ) with g,b ===========
// agg is bf16 paired-order; Wo rows permuted at prep time to match.
struct OutPack {
    const unsigned short* Aagg; const float* Ax;
    const unsigned short* Wt;   // [128][256]
    const float *bo, *bnp, *g, *bln; float* out; int M;
};

__global__ __launch_bounds__(256) void gemm_out_ln(OutPack p0, OutPack p1, int B0) {
    constexpr int K = 256, LDA = 264, LDB = 72, FTLD = 132;
    __shared__ __align__(16) char smemA[64 * LDA * 2];
    __shared__ __align__(16) unsigned short Bs[128 * LDB];
    unsigned short* As = (unsigned short*)smemA;

    OutPack p; int blk;
    if ((int)blockIdx.x < B0) { p = p0; blk = blockIdx.x; } else { p = p1; blk = blockIdx.x - B0; }

    const int tid = threadIdx.x;
    const int rbase = blk * 64;

    for (int slot = tid; slot < 64 * 32; slot += 256) {
        int row = slot >> 5, kg = slot & 31;
        int gr = rbase + row;
        short8 s8 = {0, 0, 0, 0, 0, 0, 0, 0};
        if (gr < p.M) {
            if (kg < 16) {
                s8 = *reinterpret_cast<const short8*>(p.Aagg + (size_t)gr * 128 + kg * 8);
            } else {
                const float* a = p.Ax + (size_t)gr * 128 + (kg - 16) * 8;
                float4 f0 = *reinterpret_cast<const float4*>(a);
                float4 f1 = *reinterpret_cast<const float4*>(a + 4);
                s8[0] = (short)f2bf(f0.x); s8[1] = (short)f2bf(f0.y);
                s8[2] = (short)f2bf(f0.z); s8[3] = (short)f2bf(f0.w);
                s8[4] = (short)f2bf(f1.x); s8[5] = (short)f2bf(f1.y);
                s8[6] = (short)f2bf(f1.z); s8[7] = (short)f2bf(f1.w);
            }
        }
        *reinterpret_cast<short8*>(&As[row * LDA + kg * 8]) = s8;
    }

    const int lane = tid & 63, w = tid >> 6;
    const int rb = (w >> 1) * 32, cb = (w & 1) * 64;
    const int qd = lane >> 4, l16 = lane & 15;

    f32x4 acc[2][4];
#pragma unroll
    for (int rt = 0; rt < 2; ++rt)
#pragma unroll
        for (int ct = 0; ct < 4; ++ct) { f32x4 z = {0.f,0.f,0.f,0.f}; acc[rt][ct] = z; }

    for (int kc = 0; kc < K; kc += 64) {
        __syncthreads();
        for (int slot = tid; slot < 128 * 8; slot += 256) {
            int n = slot >> 3, kg = slot & 7;
            *reinterpret_cast<short8*>(&Bs[n * LDB + kg * 8]) =
                *reinterpret_cast<const short8*>(p.Wt + (size_t)n * K + kc + kg * 8);
        }
        __syncthreads();
#pragma unroll
        for (int ks = 0; ks < 64; ks += 32) {
            short8 af[2], bfr[4];
#pragma unroll
            for (int rt = 0; rt < 2; ++rt)
                af[rt] = *reinterpret_cast<const short8*>(
                    &As[(rb + rt * 16 + l16) * LDA + kc + ks + qd * 8]);
#pragma unroll
            for (int ct = 0; ct < 4; ++ct)
                bfr[ct] = *reinterpret_cast<const short8*>(
                    &Bs[(cb + ct * 16 + l16) * LDB + ks + qd * 8]);
#pragma unroll
            for (int rt = 0; rt < 2; ++rt)
#pragma unroll
                for (int ct = 0; ct < 4; ++ct)
                    acc[rt][ct] = __builtin_amdgcn_mfma_f32_16x16x32_bf16(
                        af[rt], bfr[ct], acc[rt][ct], 0, 0, 0);
        }
    }

    __syncthreads();
    float* ftile = (float*)smemA;
#pragma unroll
    for (int ct = 0; ct < 4; ++ct) {
        int col = cb + ct * 16 + l16;
        float bv = p.bo[col] + p.bnp[col];
#pragma unroll
        for (int rt = 0; rt < 2; ++rt)
#pragma unroll
            for (int r = 0; r < 4; ++r)
                ftile[(rb + rt * 16 + qd * 4 + r) * FTLD + col] = acc[rt][ct][r] + bv;
    }
    __syncthreads();

    int r = tid >> 2, q4 = tid & 3;
    const float* rowp = &ftile[r * FTLD + q4 * 32];
    float s = 0.f, sq = 0.f;
#pragma unroll
    for (int j = 0; j < 8; ++j) {
        float4 v = *reinterpret_cast<const float4*>(rowp + j * 4);
        s += v.x + v.y + v.z + v.w;
        sq += v.x * v.x + v.y * v.y + v.z * v.z + v.w * v.w;
    }
    s += __shfl_xor(s, 1, 64);  s += __shfl_xor(s, 2, 64);
    sq += __shfl_xor(sq, 1, 64); sq += __shfl_xor(sq, 2, 64);
    float mu = s * (1.f / 128.f);
    float var = sq * (1.f / 128.f) - mu * mu;
    float rs = rsqrtf(var + 1e-5f);
    int gr = rbase + r;
    if (gr < p.M) {
#pragma unroll
        for (int j = 0; j < 8; ++j) {
            float4 v = *reinterpret_cast<const float4*>(rowp + j * 4);
            int c = q4 * 32 + j * 4;
            float4 gg = *reinterpret_cast<const float4*>(p.g + c);
            float4 bb = *reinterpret_cast<const float4*>(p.bln + c);
            float4 o;
            o.x = (v.x - mu) * rs * gg.x + bb.x;
            o.y = (v.y - mu) * rs * gg.y + bb.y;
            o.z = (v.z - mu) * rs * gg.z + bb.z;
            o.w = (v.w - mu) * rs * gg.w + bb.w;
            *reinterpret_cast<float4*>(&p.out[(size_t)gr * 128 + c]) = o;
        }
    }
}

// ================= CSR scan/scatter =================
__global__ __launch_bounds__(1024) void scan_partial(const int* c0, int N0, int* rp0, int* bs0, int B0,
                                                     const int* c1, int N1, int* rp1, int* bs1) {
    __shared__ int wsum[16];
    const int* c; int* rp; int* bs; int N; int blk;
    if ((int)blockIdx.x < B0) { c = c0; rp = rp0; bs = bs0; N = N0; blk = blockIdx.x; }
    else { c = c1; rp = rp1; bs = bs1; N = N1; blk = blockIdx.x - B0; }
    int tid = threadIdx.x, lane = tid & 63, w = tid >> 6;
    int i = blk * 1024 + tid;
    int v = (i < N) ? c[i] : 0;
    int s = v;
#pragma unroll
    for (int off = 1; off < 64; off <<= 1) {
        int t = __shfl_up(s, off, 64);
        if (lane >= off) s += t;
    }
    if (lane == 63) wsum[w] = s;
    __syncthreads();
    if (w == 0 && lane < 16) {
        int ws = wsum[lane];
#pragma unroll
        for (int off = 1; off < 16; off <<= 1) {
            int t = __shfl_up(ws, off, 64);
            if (lane >= off) ws += t;
        }
        wsum[lane] = ws;
    }
    __syncthreads();
    int wexcl = (w == 0) ? 0 : wsum[w - 1];
    if (i < N) rp[i] = wexcl + s - v;
    if (tid == 0) bs[blk] = wsum[15];
}

__global__ __launch_bounds__(128) void scan_mid(const int* bs0, int* off0, int B0, int* rpN0,
                                                const int* bs1, int* off1, int B1, int* rpN1) {
    int w = threadIdx.x >> 6, lane = threadIdx.x & 63;
    const int* bs = w ? bs1 : bs0;
    int* off = w ? off1 : off0;
    int B = w ? B1 : B0;
    int* rpN = w ? rpN1 : rpN0;
    int v = (lane < B) ? bs[lane] : 0;
    int s = v;
#pragma unroll
    for (int o = 1; o < 64; o <<= 1) {
        int t = __shfl_up(s, o, 64);
        if (lane >= o) s += t;
    }
    if (lane < B) off[lane] = s - v;
    int total = __shfl(s, B - 1, 64);
    if (lane == 0) *rpN = total;
}

__global__ __launch_bounds__(1024) void scan_add(int* rp0, int* cur0, const int* off0, int N0, int B0,
                                                 int* rp1, int* cur1, const int* off1, int N1) {
    int* rp; int* cur; const int* off; int N; int blk;
    if ((int)blockIdx.x < B0) { rp = rp0; cur = cur0; off = off0; N = N0; blk = blockIdx.x; }
    else { rp = rp1; cur = cur1; off = off1; N = N1; blk = blockIdx.x - B0; }
    int i = blk * 1024 + threadIdx.x;
    if (i < N) {
        int vv = rp[i] + off[blk];
        rp[i] = vv;
        cur[i] = vv;
    }
}

__global__ __launch_bounds__(256) void scatter_both(
    const int* __restrict__ s0, const int* __restrict__ d0, int E0, int* cur0, int* pos0, int* srcs0,
    const int* __restrict__ s1, const int* __restrict__ d1, int E1, int* cur1, int* pos1, int* srcs1) {
    int t = blockIdx.x * 256 + threadIdx.x;
    if (t < E0) {
        int p = atomicAdd(&cur0[d0[t]], 1);
        pos0[t] = p;
        srcs0[p] = s0[t];
    } else if (t < E0 + E1) {
        int tt = t - E0;
        int p = atomicAdd(&cur1[d1[tt]], 1);
        pos1[tt] = p;
        srcs1[p] = s1[tt];
    }
}

// ============ CSR gather attention: 1 wave/dst, 2 edges/iter (ILP), paired cols ====
struct AttnPack {
    const unsigned int *q, *kv, *e;   // paired bf16x2 layouts; e in CSR order
    const int *srcs;                  // padded with zeros past E
    const int *row_ptr;
    unsigned int* agg; int N;
};

__global__ __launch_bounds__(256) void attn_gather(AttnPack a0, AttnPack a1, int B0) {
    AttnPack a; int blk;
    if ((int)blockIdx.x < B0) { a = a0; blk = blockIdx.x; } else { a = a1; blk = blockIdx.x - B0; }
    int dst = blk * 4 + (threadIdx.x >> 6);
    if (dst >= a.N) return;
    int lane = threadIdx.x & 63;

    unsigned qp = a.q[(size_t)dst * 64 + lane];
    float qlo = bflo(qp), qhi = bfhi(qp);
    int beg = a.row_ptr[dst], end = a.row_ptr[dst + 1];
    float denl = 0.f, denh = 0.f, accl = 0.f, acch = 0.f;

    // prologue: load pair (beg, beg+1). srcs padded with 0 past E (node 0 = finite
    // data); e padded with 4 zeroed rows past E. Invalid second-edge contributions
    // are masked to 0 after exp.
    int s0 = a.srcs[beg], s1 = a.srcs[beg + 1];
    unsigned k0 = a.kv[(size_t)s0 * 128 + lane];
    unsigned v0 = a.kv[(size_t)s0 * 128 + 64 + lane];
    unsigned e0 = a.e[(size_t)beg * 64 + lane];
    unsigned k1 = a.kv[(size_t)s1 * 128 + lane];
    unsigned v1 = a.kv[(size_t)s1 * 128 + 64 + lane];
    unsigned e1 = a.e[(size_t)(beg + 1) * 64 + lane];

    for (int i = beg; i < end; i += 2) {
        // prefetch next pair (always safe due to padding)
        int sn0 = a.srcs[i + 2], sn1 = a.srcs[i + 3];
        unsigned kn0 = a.kv[(size_t)sn0 * 128 + lane];
        unsigned vn0 = a.kv[(size_t)sn0 * 128 + 64 + lane];
        unsigned en0 = a.e[(size_t)(i + 2) * 64 + lane];
        unsigned kn1 = a.kv[(size_t)sn1 * 128 + lane];
        unsigned vn1 = a.kv[(size_t)sn1 * 128 + 64 + lane];
        unsigned en1 = a.e[(size_t)(i + 3) * 64 + lane];

        float e0l = bflo(e0), e0h = bfhi(e0);
        float e1l = bflo(e1), e1h = bfhi(e1);
        float p0l = qlo * (bflo(k0) + e0l), p0h = qhi * (bfhi(k0) + e0h);
        float p1l = qlo * (bflo(k1) + e1l), p1h = qhi * (bfhi(k1) + e1h);
        // 4 independent 16-lane reduction trees (ILP = 4)
#pragma unroll
        for (int m = 1; m < 16; m <<= 1) {
            p0l += __shfl_xor(p0l, m, 64);
            p0h += __shfl_xor(p0h, m, 64);
            p1l += __shfl_xor(p1l, m, 64);
            p1h += __shfl_xor(p1h, m, 64);
        }
        float x0l = __expf(p0l * 0.25f), x0h = __expf(p0h * 0.25f);
        float x1l = __expf(p1l * 0.25f), x1h = __expf(p1h * 0.25f);
        bool second = (i + 1 < end);
        x1l = second ? x1l : 0.f;
        x1h = second ? x1h : 0.f;
        denl += x0l + x1l;
        denh += x0h + x1h;
        accl += x0l * (bflo(v0) + e0l) + x1l * (bflo(v1) + e1l);
        acch += x0h * (bfhi(v0) + e0h) + x1h * (bfhi(v1) + e1h);
        k0 = kn0; v0 = vn0; e0 = en0;
        k1 = kn1; v1 = vn1; e1 = en1;
    }
    float ol = denl > 0.f ? accl / denl : 0.f;
    float oh = denh > 0.f ? acch / denh : 0.f;
    a.agg[(size_t)dst * 64 + lane] = (unsigned)f2bf(ol) | ((unsigned)f2bf(oh) << 16);
}

extern "C" void kernel_launch(void* const* d_in, const int* in_sizes, int n_in,
                              void* d_out, int out_size, void* d_ws, size_t ws_size,
                              hipStream_t stream) {
    const float* x_pc  = (const float*)d_in[0];
    const float* x_gr  = (const float*)d_in[1];
    const float* ea_pp = (const float*)d_in[2];
    const float* ea_pg = (const float*)d_in[3];
    const int* ei_pp   = (const int*)d_in[4];
    const int* ei_pg   = (const int*)d_in[5];
    const float *Wq_pp = (const float*)d_in[6],  *bq_pp = (const float*)d_in[7];
    const float *Wk_pp = (const float*)d_in[8],  *bk_pp = (const float*)d_in[9];
    const float *Wv_pp = (const float*)d_in[10], *bv_pp = (const float*)d_in[11];
    const float *We_pp = (const float*)d_in[12], *be_pp = (const float*)d_in[13];
    const float *Wo_pp = (const float*)d_in[14], *bo_pp = (const float*)d_in[15];
    const float *Wq_pg = (const float*)d_in[16], *bq_pg = (const float*)d_in[17];
    const float *Wk_pg = (const float*)d_in[18], *bk_pg = (const float*)d_in[19];
    const float *Wv_pg = (const float*)d_in[20], *bv_pg = (const float*)d_in[21];
    const float *We_pg = (const float*)d_in[22], *be_pg = (const float*)d_in[23];
    const float *Wo_pg = (const float*)d_in[24], *bo_pg = (const float*)d_in[25];
    const float *Wnp_pc = (const float*)d_in[26], *bnp_pc = (const float*)d_in[27];
    const float *g_pc   = (const float*)d_in[28], *bln_pc = (const float*)d_in[29];
    const float *Wnp_gr = (const float*)d_in[30], *bnp_gr = (const float*)d_in[31];
    const float *g_gr   = (const float*)d_in[32], *bln_gr = (const float*)d_in[33];

    const int N_pc = in_sizes[0] / 128;
    const int N_gr = in_sizes[1] / 128;
    const int E_pp = in_sizes[4] / 2;
    const int E_pg = in_sizes[5] / 2;

    char* ws = (char*)d_ws;
    size_t off = 0;
    auto alloc = [&](size_t bytes) -> char* {
        char* p = ws + off;
        off += (bytes + 255) & ~(size_t)255;
        return p;
    };
    unsigned short* Wt_q_pp = (unsigned short*)alloc(128 * 128 * 2);
    unsigned short* Wt_k_pp = (unsigned short*)alloc(128 * 128 * 2);
    unsigned short* Wt_v_pp = (unsigned short*)alloc(128 * 128 * 2);
    unsigned short* Wt_k_pg = (unsigned short*)alloc(128 * 128 * 2);
    unsigned short* Wt_v_pg = (unsigned short*)alloc(128 * 128 * 2);
    unsigned short* Wt_q_pg = (unsigned short*)alloc(128 * 128 * 2);
    unsigned short* Wt_e_pp = (unsigned short*)alloc(64 * 128 * 2);
    unsigned short* Wt_e_pg = (unsigned short*)alloc(64 * 128 * 2);
    unsigned short* Wt_cat_pp = (unsigned short*)alloc(256 * 128 * 2);
    unsigned short* Wt_cat_gr = (unsigned short*)alloc(256 * 128 * 2);

    unsigned int* q_pp  = (unsigned int*)alloc((size_t)N_pc * 64 * 4);
    unsigned int* kv_pp = (unsigned int*)alloc((size_t)N_pc * 128 * 4);
    unsigned int* q_pg  = (unsigned int*)alloc((size_t)N_gr * 64 * 4);
    unsigned int* kv_pg = (unsigned int*)alloc((size_t)N_pc * 128 * 4);
    unsigned int* e_pp  = (unsigned int*)alloc((size_t)(E_pp + 4) * 64 * 4);  // +4 pad rows
    unsigned int* e_pg  = (unsigned int*)alloc((size_t)(E_pg + 4) * 64 * 4);
    unsigned int* agg_pp = (unsigned int*)alloc((size_t)N_pc * 64 * 4);
    unsigned int* agg_pg = (unsigned int*)alloc((size_t)N_gr * 64 * 4);
    int* row_ptr_pp = (int*)alloc((size_t)(N_pc + 1) * 4);
    int* cursor_pp  = (int*)alloc((size_t)N_pc * 4);
    int* pos_pp     = (int*)alloc((size_t)E_pp * 4);
    int* row_ptr_pg = (int*)alloc((size_t)(N_gr + 1) * 4);
    int* cursor_pg  = (int*)alloc((size_t)N_gr * 4);
    int* pos_pg     = (int*)alloc((size_t)E_pg * 4);
    int* bsum_pp    = (int*)alloc(64 * 4);
    int* boff_pp    = (int*)alloc(64 * 4);
    int* bsum_pg    = (int*)alloc(64 * 4);
    int* boff_pg    = (int*)alloc(64 * 4);
    char* zbase = ws + off;   // zero region: counts + padded srcs
    int* counts_pp = (int*)alloc((size_t)N_pc * 4);
    int* counts_pg = (int*)alloc((size_t)N_gr * 4);
    int* srcs_pp   = (int*)alloc((size_t)(E_pp + 8) * 4);  // pads stay zero
    int* srcs_pg   = (int*)alloc((size_t)(E_pg + 8) * 4);
    size_t zbytes = (size_t)((ws + off) - zbase);
    hipMemsetAsync(zbase, 0, zbytes, stream);
    // zero the e pad rows (read by the 2-edge pipeline past E; must be finite)
    hipMemsetAsync(e_pp + (size_t)E_pp * 64, 0, 4 * 64 * 4, stream);
    hipMemsetAsync(e_pg + (size_t)E_pg * 64, 0, 4 * 64 * 4, stream);

    float* out_pc = (float*)d_out;
    float* out_gr = out_pc + (size_t)N_pc * 128;

    const int* src_pp = ei_pp;
    const int* dst_pp = ei_pp + E_pp;
    const int* src_pg = ei_pg;
    const int* dst_pg = ei_pg + E_pg;

    // ---- weight prep + degree count (one launch) ----
    WPack wp;
    wp.w[0]  = {Wq_pp, Wt_q_pp, 128, 128, 0, 0};
    wp.w[1]  = {Wk_pp, Wt_k_pp, 128, 128, 0, 0};
    wp.w[2]  = {Wv_pp, Wt_v_pp, 128, 128, 0, 0};
    wp.w[3]  = {Wk_pg, Wt_k_pg, 128, 128, 0, 0};
    wp.w[4]  = {Wv_pg, Wt_v_pg, 128, 128, 0, 0};
    wp.w[5]  = {Wq_pg, Wt_q_pg, 128, 128, 0, 0};
    wp.w[6]  = {We_pp, Wt_e_pp, 64, 64, 0, 0};
    wp.w[7]  = {We_pg, Wt_e_pg, 64, 64, 0, 0};
    wp.w[8]  = {Wo_pp, Wt_cat_pp, 128, 256, 0, 1};    // paired-row perm (agg is paired)
    wp.w[9]  = {Wnp_pc, Wt_cat_pp, 128, 256, 128, 0};
    wp.w[10] = {Wo_pg, Wt_cat_gr, 128, 256, 0, 1};
    wp.w[11] = {Wnp_gr, Wt_cat_gr, 128, 256, 128, 0};
    const int NPREP = 48;
    const int gE = (E_pp + E_pg + 255) / 256;
    prep_and_count<<<NPREP + gE, 256, 0, stream>>>(wp, dst_pp, E_pp, counts_pp,
                                                   dst_pg, E_pg, counts_pg, NPREP);

    // ---- CSR build ----
    const int Bs_pp = (N_pc + 1023) / 1024, Bs_pg = (N_gr + 1023) / 1024;
    scan_partial<<<Bs_pp + Bs_pg, 1024, 0, stream>>>(counts_pp, N_pc, row_ptr_pp, bsum_pp, Bs_pp,
                                                     counts_pg, N_gr, row_ptr_pg, bsum_pg);
    scan_mid<<<1, 128, 0, stream>>>(bsum_pp, boff_pp, Bs_pp, &row_ptr_pp[N_pc],
                                    bsum_pg, boff_pg, Bs_pg, &row_ptr_pg[N_gr]);
    scan_add<<<Bs_pp + Bs_pg, 1024, 0, stream>>>(row_ptr_pp, cursor_pp, boff_pp, N_pc, Bs_pp,
                                                 row_ptr_pg, cursor_pg, boff_pg, N_gr);
    scatter_both<<<gE, 256, 0, stream>>>(src_pp, dst_pp, E_pp, cursor_pp, pos_pp, srcs_pp,
                                         src_pg, dst_pg, E_pg, cursor_pg, pos_pg, srcs_pg);

    // ---- merged node + edge projections (one launch, overlapped) ----
    EdgeJob ej0 = {ea_pp, Wt_e_pp, be_pp, pos_pp, e_pp, E_pp};
    EdgeJob ej1 = {ea_pg, Wt_e_pg, be_pg, pos_pg, e_pg, E_pg};
    NodeJob nj0{};
    nj0.A = x_pc; nj0.M = N_pc; nj0.nout = 5;
    nj0.d[0] = {Wt_q_pp, bq_pp, q_pp, 64, 0};
    nj0.d[1] = {Wt_k_pp, bk_pp, kv_pp, 128, 0};
    nj0.d[2] = {Wt_v_pp, bv_pp, kv_pp, 128, 64};
    nj0.d[3] = {Wt_k_pg, bk_pg, kv_pg, 128, 0};
    nj0.d[4] = {Wt_v_pg, bv_pg, kv_pg, 128, 64};
    NodeJob nj1{};
    nj1.A = x_gr; nj1.M = N_gr; nj1.nout = 1;
    nj1.d[0] = {Wt_q_pg, bq_pg, q_pg, 64, 0};
    int BE0 = (E_pp + 127) / 128, BE1 = (E_pg + 127) / 128;
    int BN0 = (N_pc + 127) / 128, BN1 = (N_gr + 127) / 128;
    gemm_ne<<<BE0 + BE1 + BN0 + BN1, 256, 0, stream>>>(ej0, ej1, nj0, nj1, BE0, BE1, BN0);

    // ---- gather attention: 1 wave per dst, 2 edges per iteration ----
    AttnPack ap0 = {q_pp, kv_pp, e_pp, srcs_pp, row_ptr_pp, agg_pp, N_pc};
    AttnPack ap1 = {q_pg, kv_pg, e_pg, srcs_pg, row_ptr_pg, agg_pg, N_gr};
    int Ba0 = (N_pc + 3) / 4, Ba1 = (N_gr + 3) / 4;
    attn_gather<<<Ba0 + Ba1, 256, 0, stream>>>(ap0, ap1, Ba0);

    // ---- output GEMM + residual + LayerNorm ----
    OutPack op0 = {(const unsigned short*)agg_pp, x_pc, Wt_cat_pp, bo_pp, bnp_pc, g_pc, bln_pc, out_pc, N_pc};
    OutPack op1 = {(const unsigned short*)agg_pg, x_gr, Wt_cat_gr, bo_pg, bnp_gr, g_gr, bln_gr, out_gr, N_gr};
    int Bo0 = (N_pc + 63) / 64, Bo1 = (N_gr + 63) / 64;
    gemm_out_ln<<<Bo0 + Bo1, 256, 0, stream>>>(op0, op1, Bo0);
}

// Round 7
// 515.186 us; speedup vs baseline: 1.0523x; 1.0523x over previous
//
#include <hip/hip_runtime.h>
#include <hip/hip_bf16.h>
#include <stdint.h>

typedef short short8 __attribute__((ext_vector_type(8)));
typedef float f32x4 __attribute__((ext_vector_type(4)));

// ---------- helpers ----------
__device__ __forceinline__ unsigned short f2bf(float x) {
    unsigned u = __float_as_uint(x);
    u += 0x7fffu + ((u >> 16) & 1u);   // RNE
    return (unsigned short)(u >> 16);
}
__device__ __forceinline__ float bflo(unsigned u) { return __uint_as_float(u << 16); }
__device__ __forceinline__ float bfhi(unsigned u) { return __uint_as_float(u & 0xffff0000u); }

// ---------- weight prep (+ degree count, fused) ----------
// W [K][128] f32 -> Wt [128][ldd] bf16 at koff; perm=1 applies paired-row permutation
struct WDesc { const float* src; unsigned short* dst; int K, ldd, koff, perm; };
struct WPack { WDesc w[12]; };

__global__ __launch_bounds__(256) void prep_and_count(WPack p,
        const int* __restrict__ d0, int E0, int* c0,
        const int* __restrict__ d1, int E1, int* c1, int nPrep) {
    if ((int)blockIdx.x < nPrep) {
        int wi = blockIdx.x >> 2, chunk = blockIdx.x & 3;
        WDesc d = p.w[wi];
        int total = d.K * 128, cs = total >> 2;
        int lo = chunk * cs, hi = lo + cs;
        for (int i = lo + threadIdx.x; i < hi; i += 256) {
            int n = i / d.K, k = i - n * d.K;
            int kk = d.perm ? (2 * (k & 63) + (k >> 6)) : k;
            d.dst[(size_t)n * d.ldd + d.koff + kk] = f2bf(d.src[(size_t)k * 128 + n]);
        }
    } else {
        int t = (blockIdx.x - nPrep) * 256 + threadIdx.x;
        if (t < E0) atomicAdd(&c0[d0[t]], 1);
        else if (t < E0 + E1) atomicAdd(&c1[d1[t - E0]], 1);
    }
}

// ================= node GEMM: paired bf16 outputs, two inputs in one launch =======
struct NodeOut { const unsigned short* Wt; const float* bias; unsigned int* out; int ldc, coloff; };
struct NodePack { NodeOut d[5]; int nout; };

__global__ __launch_bounds__(256) void gemm_node(const float* __restrict__ A0, int M0, NodePack p0,
                                                 int B0,
                                                 const float* __restrict__ A1, int M1, NodePack p1) {
    constexpr int K = 128, LDA = 136, LDB = 72, TLD = 133;
    __shared__ __align__(16) unsigned short As[64 * LDA];
    __shared__ __align__(16) unsigned short Bs[128 * LDB];  // also epilogue tile (TLD)

    const float* A; int M; NodePack dp; int blk;
    if ((int)blockIdx.x < B0) { A = A0; M = M0; dp = p0; blk = blockIdx.x; }
    else { A = A1; M = M1; dp = p1; blk = blockIdx.x - B0; }

    const int tid = threadIdx.x;
    const int rbase = blk * 64;

    for (int slot = tid; slot < 64 * 16; slot += 256) {
        int row = slot >> 4, kg = slot & 15;
        int gr = rbase + row;
        short8 s8 = {0, 0, 0, 0, 0, 0, 0, 0};
        if (gr < M) {
            const float* a = A + (size_t)gr * K + kg * 8;
            float4 f0 = *reinterpret_cast<const float4*>(a);
            float4 f1 = *reinterpret_cast<const float4*>(a + 4);
            s8[0] = (short)f2bf(f0.x); s8[1] = (short)f2bf(f0.y);
            s8[2] = (short)f2bf(f0.z); s8[3] = (short)f2bf(f0.w);
            s8[4] = (short)f2bf(f1.x); s8[5] = (short)f2bf(f1.y);
            s8[6] = (short)f2bf(f1.z); s8[7] = (short)f2bf(f1.w);
        }
        *reinterpret_cast<short8*>(&As[row * LDA + kg * 8]) = s8;
    }

    const int lane = tid & 63, w = tid >> 6;
    const int rb = (w >> 1) * 32, cb = (w & 1) * 64;
    const int qd = lane >> 4, l16 = lane & 15;

    for (int o = 0; o < dp.nout; ++o) {
        NodeOut d = dp.d[o];
        f32x4 acc[2][4];
#pragma unroll
        for (int rt = 0; rt < 2; ++rt)
#pragma unroll
            for (int ct = 0; ct < 4; ++ct) { f32x4 z = {0.f,0.f,0.f,0.f}; acc[rt][ct] = z; }

        for (int kc = 0; kc < K; kc += 64) {
            __syncthreads();
            for (int slot = tid; slot < 128 * 8; slot += 256) {
                int n = slot >> 3, kg = slot & 7;
                *reinterpret_cast<short8*>(&Bs[n * LDB + kg * 8]) =
                    *reinterpret_cast<const short8*>(d.Wt + (size_t)n * K + kc + kg * 8);
            }
            __syncthreads();
#pragma unroll
            for (int ks = 0; ks < 64; ks += 32) {
                short8 af[2], bfr[4];
#pragma unroll
                for (int rt = 0; rt < 2; ++rt)
                    af[rt] = *reinterpret_cast<const short8*>(
                        &As[(rb + rt * 16 + l16) * LDA + kc + ks + qd * 8]);
#pragma unroll
                for (int ct = 0; ct < 4; ++ct)
                    bfr[ct] = *reinterpret_cast<const short8*>(
                        &Bs[(cb + ct * 16 + l16) * LDB + ks + qd * 8]);
#pragma unroll
                for (int rt = 0; rt < 2; ++rt)
#pragma unroll
                    for (int ct = 0; ct < 4; ++ct)
                        acc[rt][ct] = __builtin_amdgcn_mfma_f32_16x16x32_bf16(
                            af[rt], bfr[ct], acc[rt][ct], 0, 0, 0);
            }
        }

        // epilogue: acc -> LDS tile -> paired u32 stores (16B/lane)
        __syncthreads();
        unsigned short* tile = Bs;
#pragma unroll
        for (int ct = 0; ct < 4; ++ct) {
            int col = cb + ct * 16 + l16;
            float bv = d.bias[col];
#pragma unroll
            for (int rt = 0; rt < 2; ++rt)
#pragma unroll
                for (int r = 0; r < 4; ++r)
                    tile[(rb + rt * 16 + qd * 4 + r) * TLD + col] = f2bf(acc[rt][ct][r] + bv);
        }
        __syncthreads();
#pragma unroll
        for (int rep = 0; rep < 4; ++rep) {
            int lrow = (tid >> 4) + rep * 16, seg = tid & 15;
            int gr = rbase + lrow;
            if (gr < M) {
                uint4 pk;
#pragma unroll
                for (int j = 0; j < 4; ++j) {
                    int pcol = seg * 4 + j;
                    unsigned lo16 = tile[lrow * TLD + pcol];
                    unsigned hi16 = tile[lrow * TLD + pcol + 64];
                    ((unsigned*)&pk)[j] = lo16 | (hi16 << 16);
                }
                *reinterpret_cast<uint4*>(&d.out[(size_t)gr * d.ldc + d.coloff + seg * 4]) = pk;
            }
        }
    }
}

// ====== edge GEMM: wave-private 32-row tiles, NO barriers, direct frag loads ======
// Wave w of block b owns edge rows [b*128+w*32, +32). A fragments loaded straight
// from global in MFMA layout (no LDS, no staging sync). B in LDS (loaded once).
// Output packed to paired u32 in registers and scattered to CSR position pos[edge].
struct EdgePack {
    const float* A; const unsigned short* Wt; const float* bias;
    const int* pos; unsigned int* out; int M;
};

__global__ __launch_bounds__(256) void gemm_edge(EdgePack p0, EdgePack p1, int B0) {
    constexpr int LDB = 72;
    __shared__ __align__(16) unsigned short Bs[128 * LDB];

    EdgePack p; int blk;
    if ((int)blockIdx.x < B0) { p = p0; blk = blockIdx.x; } else { p = p1; blk = blockIdx.x - B0; }

    const int tid = threadIdx.x;
    // stage B once: [outcol n][k]
    for (int slot = tid; slot < 128 * 8; slot += 256) {
        int n = slot >> 3, k8 = slot & 7;
        *reinterpret_cast<short8*>(&Bs[n * LDB + k8 * 8]) =
            *reinterpret_cast<const short8*>(p.Wt + (size_t)n * 64 + k8 * 8);
    }
    __syncthreads();   // only barrier in the kernel

    const int lane = tid & 63, w = tid >> 6;
    const int qd = lane >> 4, l16 = lane & 15;
    const int rbase = blk * 128 + w * 32;      // wave-private rows
    if (rbase >= p.M) return;

    // --- A fragments direct from global (8 independent float4 loads) ---
    float4 fa[4][2];
#pragma unroll
    for (int rt = 0; rt < 2; ++rt)
#pragma unroll
        for (int ks = 0; ks < 2; ++ks) {
            int gr = rbase + rt * 16 + l16;
            int grc = gr < p.M ? gr : p.M - 1;    // clamp: finite garbage, stores guarded
            const float* a = p.A + (size_t)grc * 64 + ks * 32 + qd * 8;
            fa[rt * 2 + ks][0] = *reinterpret_cast<const float4*>(a);
            fa[rt * 2 + ks][1] = *reinterpret_cast<const float4*>(a + 4);
        }

    short8 af[2][2];
#pragma unroll
    for (int rt = 0; rt < 2; ++rt)
#pragma unroll
        for (int ks = 0; ks < 2; ++ks) {
            float4 f0 = fa[rt * 2 + ks][0], f1 = fa[rt * 2 + ks][1];
            short8 s;
            s[0] = (short)f2bf(f0.x); s[1] = (short)f2bf(f0.y);
            s[2] = (short)f2bf(f0.z); s[3] = (short)f2bf(f0.w);
            s[4] = (short)f2bf(f1.x); s[5] = (short)f2bf(f1.y);
            s[6] = (short)f2bf(f1.z); s[7] = (short)f2bf(f1.w);
            af[rt][ks] = s;
        }

    // --- MFMA: 2 rt x 8 ct x 2 ks = 32 ---
    f32x4 acc[2][8];
#pragma unroll
    for (int rt = 0; rt < 2; ++rt)
#pragma unroll
        for (int ct = 0; ct < 8; ++ct) { f32x4 z = {0.f,0.f,0.f,0.f}; acc[rt][ct] = z; }
#pragma unroll
    for (int ks = 0; ks < 2; ++ks)
#pragma unroll
        for (int ct = 0; ct < 8; ++ct) {
            short8 bf = *reinterpret_cast<const short8*>(
                &Bs[(ct * 16 + l16) * LDB + ks * 32 + qd * 8]);
            acc[0][ct] = __builtin_amdgcn_mfma_f32_16x16x32_bf16(af[0][ks], bf, acc[0][ct], 0, 0, 0);
            acc[1][ct] = __builtin_amdgcn_mfma_f32_16x16x32_bf16(af[1][ks], bf, acc[1][ct], 0, 0, 0);
        }

    // --- epilogue: in-register pair pack, scattered u32 stores ---
    float blo[4], bhi[4];
#pragma unroll
    for (int ct = 0; ct < 4; ++ct) {
        blo[ct] = p.bias[ct * 16 + l16];
        bhi[ct] = p.bias[64 + ct * 16 + l16];
    }
#pragma unroll
    for (int rt = 0; rt < 2; ++rt)
#pragma unroll
        for (int r = 0; r < 4; ++r) {
            int gr = rbase + rt * 16 + qd * 4 + r;
            if (gr < p.M) {
                int dpos = p.pos[gr];
                unsigned int* dst = p.out + (size_t)dpos * 64 + l16;
#pragma unroll
                for (int ct = 0; ct < 4; ++ct) {
                    unsigned lo = f2bf(acc[rt][ct][r] + blo[ct]);
                    unsigned hi = f2bf(acc[rt][ct + 4][r] + bhi[ct]);
                    dst[ct * 16] = lo | (hi << 16);
                }
            }
        }
}

// ===== output GEMM: out = LN( [agg|x] @ [Wo;Wnp] + bo + bnp ) with g,b ===========
// agg is bf16 paired-order; Wo rows permuted at prep time to match.
struct OutPack {
    const unsigned short* Aagg; const float* Ax;
    const unsigned short* Wt;   // [128][256]
    const float *bo, *bnp, *g, *bln; float* out; int M;
};

__global__ __launch_bounds__(256) void gemm_out_ln(OutPack p0, OutPack p1, int B0) {
    constexpr int K = 256, LDA = 264, LDB = 72, FTLD = 132;
    __shared__ __align__(16) char smemA[64 * LDA * 2];
    __shared__ __align__(16) unsigned short Bs[128 * LDB];
    unsigned short* As = (unsigned short*)smemA;

    OutPack p; int blk;
    if ((int)blockIdx.x < B0) { p = p0; blk = blockIdx.x; } else { p = p1; blk = blockIdx.x - B0; }

    const int tid = threadIdx.x;
    const int rbase = blk * 64;

    for (int slot = tid; slot < 64 * 32; slot += 256) {
        int row = slot >> 5, kg = slot & 31;
        int gr = rbase + row;
        short8 s8 = {0, 0, 0, 0, 0, 0, 0, 0};
        if (gr < p.M) {
            if (kg < 16) {
                s8 = *reinterpret_cast<const short8*>(p.Aagg + (size_t)gr * 128 + kg * 8);
            } else {
                const float* a = p.Ax + (size_t)gr * 128 + (kg - 16) * 8;
                float4 f0 = *reinterpret_cast<const float4*>(a);
                float4 f1 = *reinterpret_cast<const float4*>(a + 4);
                s8[0] = (short)f2bf(f0.x); s8[1] = (short)f2bf(f0.y);
                s8[2] = (short)f2bf(f0.z); s8[3] = (short)f2bf(f0.w);
                s8[4] = (short)f2bf(f1.x); s8[5] = (short)f2bf(f1.y);
                s8[6] = (short)f2bf(f1.z); s8[7] = (short)f2bf(f1.w);
            }
        }
        *reinterpret_cast<short8*>(&As[row * LDA + kg * 8]) = s8;
    }

    const int lane = tid & 63, w = tid >> 6;
    const int rb = (w >> 1) * 32, cb = (w & 1) * 64;
    const int qd = lane >> 4, l16 = lane & 15;

    f32x4 acc[2][4];
#pragma unroll
    for (int rt = 0; rt < 2; ++rt)
#pragma unroll
        for (int ct = 0; ct < 4; ++ct) { f32x4 z = {0.f,0.f,0.f,0.f}; acc[rt][ct] = z; }

    for (int kc = 0; kc < K; kc += 64) {
        __syncthreads();
        for (int slot = tid; slot < 128 * 8; slot += 256) {
            int n = slot >> 3, kg = slot & 7;
            *reinterpret_cast<short8*>(&Bs[n * LDB + kg * 8]) =
                *reinterpret_cast<const short8*>(p.Wt + (size_t)n * K + kc + kg * 8);
        }
        __syncthreads();
#pragma unroll
        for (int ks = 0; ks < 64; ks += 32) {
            short8 af[2], bfr[4];
#pragma unroll
            for (int rt = 0; rt < 2; ++rt)
                af[rt] = *reinterpret_cast<const short8*>(
                    &As[(rb + rt * 16 + l16) * LDA + kc + ks + qd * 8]);
#pragma unroll
            for (int ct = 0; ct < 4; ++ct)
                bfr[ct] = *reinterpret_cast<const short8*>(
                    &Bs[(cb + ct * 16 + l16) * LDB + ks + qd * 8]);
#pragma unroll
            for (int rt = 0; rt < 2; ++rt)
#pragma unroll
                for (int ct = 0; ct < 4; ++ct)
                    acc[rt][ct] = __builtin_amdgcn_mfma_f32_16x16x32_bf16(
                        af[rt], bfr[ct], acc[rt][ct], 0, 0, 0);
        }
    }

    __syncthreads();
    float* ftile = (float*)smemA;
#pragma unroll
    for (int ct = 0; ct < 4; ++ct) {
        int col = cb + ct * 16 + l16;
        float bv = p.bo[col] + p.bnp[col];
#pragma unroll
        for (int rt = 0; rt < 2; ++rt)
#pragma unroll
            for (int r = 0; r < 4; ++r)
                ftile[(rb + rt * 16 + qd * 4 + r) * FTLD + col] = acc[rt][ct][r] + bv;
    }
    __syncthreads();

    int r = tid >> 2, q4 = tid & 3;
    const float* rowp = &ftile[r * FTLD + q4 * 32];
    float s = 0.f, sq = 0.f;
#pragma unroll
    for (int j = 0; j < 8; ++j) {
        float4 v = *reinterpret_cast<const float4*>(rowp + j * 4);
        s += v.x + v.y + v.z + v.w;
        sq += v.x * v.x + v.y * v.y + v.z * v.z + v.w * v.w;
    }
    s += __shfl_xor(s, 1, 64);  s += __shfl_xor(s, 2, 64);
    sq += __shfl_xor(sq, 1, 64); sq += __shfl_xor(sq, 2, 64);
    float mu = s * (1.f / 128.f);
    float var = sq * (1.f / 128.f) - mu * mu;
    float rs = rsqrtf(var + 1e-5f);
    int gr = rbase + r;
    if (gr < p.M) {
#pragma unroll
        for (int j = 0; j < 8; ++j) {
            float4 v = *reinterpret_cast<const float4*>(rowp + j * 4);
            int c = q4 * 32 + j * 4;
            float4 gg = *reinterpret_cast<const float4*>(p.g + c);
            float4 bb = *reinterpret_cast<const float4*>(p.bln + c);
            float4 o;
            o.x = (v.x - mu) * rs * gg.x + bb.x;
            o.y = (v.y - mu) * rs * gg.y + bb.y;
            o.z = (v.z - mu) * rs * gg.z + bb.z;
            o.w = (v.w - mu) * rs * gg.w + bb.w;
            *reinterpret_cast<float4*>(&p.out[(size_t)gr * 128 + c]) = o;
        }
    }
}

// ================= CSR scan/scatter =================
__global__ __launch_bounds__(1024) void scan_partial(const int* c0, int N0, int* rp0, int* bs0, int B0,
                                                     const int* c1, int N1, int* rp1, int* bs1) {
    __shared__ int wsum[16];
    const int* c; int* rp; int* bs; int N; int blk;
    if ((int)blockIdx.x < B0) { c = c0; rp = rp0; bs = bs0; N = N0; blk = blockIdx.x; }
    else { c = c1; rp = rp1; bs = bs1; N = N1; blk = blockIdx.x - B0; }
    int tid = threadIdx.x, lane = tid & 63, w = tid >> 6;
    int i = blk * 1024 + tid;
    int v = (i < N) ? c[i] : 0;
    int s = v;
#pragma unroll
    for (int off = 1; off < 64; off <<= 1) {
        int t = __shfl_up(s, off, 64);
        if (lane >= off) s += t;
    }
    if (lane == 63) wsum[w] = s;
    __syncthreads();
    if (w == 0 && lane < 16) {
        int ws = wsum[lane];
#pragma unroll
        for (int off = 1; off < 16; off <<= 1) {
            int t = __shfl_up(ws, off, 64);
            if (lane >= off) ws += t;
        }
        wsum[lane] = ws;
    }
    __syncthreads();
    int wexcl = (w == 0) ? 0 : wsum[w - 1];
    if (i < N) rp[i] = wexcl + s - v;
    if (tid == 0) bs[blk] = wsum[15];
}

// merged scan_mid + scan_add: each block redundantly prefix-sums the <=64 block
// sums in wave 0 (cheap), then applies its offset. Block 0 writes the total.
__global__ __launch_bounds__(1024) void scan_midadd(
        int* rp0, int* cur0, const int* bs0, int N0, int B0, int* rpN0,
        int* rp1, int* cur1, const int* bs1, int N1, int B1, int* rpN1) {
    __shared__ int sh_off, sh_tot;
    int* rp; int* cur; const int* bs; int N; int B; int* rpN; int blk;
    if ((int)blockIdx.x < B0) { rp = rp0; cur = cur0; bs = bs0; N = N0; B = B0; rpN = rpN0; blk = blockIdx.x; }
    else { rp = rp1; cur = cur1; bs = bs1; N = N1; B = B1; rpN = rpN1; blk = blockIdx.x - B0; }
    int tid = threadIdx.x;
    if (tid < 64) {
        int lane = tid;
        int v = (lane < B) ? bs[lane] : 0;
        int s = v;
#pragma unroll
        for (int o = 1; o < 64; o <<= 1) {
            int t = __shfl_up(s, o, 64);
            if (lane >= o) s += t;
        }
        if (lane == blk) sh_off = s - v;   // exclusive prefix at this block (blk < 64)
        if (lane == 63) sh_tot = s;        // grand total
    }
    __syncthreads();
    int i = blk * 1024 + tid;
    if (i < N) {
        int vv = rp[i] + sh_off;
        rp[i] = vv;
        cur[i] = vv;
    }
    if (blk == 0 && tid == 0) *rpN = sh_tot;
}

__global__ __launch_bounds__(256) void scatter_both(
    const int* __restrict__ s0, const int* __restrict__ d0, int E0, int* cur0, int* pos0, int* srcs0,
    const int* __restrict__ s1, const int* __restrict__ d1, int E1, int* cur1, int* pos1, int* srcs1) {
    int t = blockIdx.x * 256 + threadIdx.x;
    if (t < E0) {
        int p = atomicAdd(&cur0[d0[t]], 1);
        pos0[t] = p;
        srcs0[p] = s0[t];
    } else if (t < E0 + E1) {
        int tt = t - E0;
        int p = atomicAdd(&cur1[d1[tt]], 1);
        pos1[tt] = p;
        srcs1[p] = s1[tt];
    }
}

// ============ CSR gather attention: 1 wave/dst, 2 edges/iter (ILP), paired cols ====
struct AttnPack {
    const unsigned int *q, *kv, *e;   // paired bf16x2 layouts; e in CSR order
    const int *srcs;                  // padded with zeros past E
    const int *row_ptr;
    unsigned int* agg; int N;
};

__global__ __launch_bounds__(256) void attn_gather(AttnPack a0, AttnPack a1, int B0) {
    AttnPack a; int blk;
    if ((int)blockIdx.x < B0) { a = a0; blk = blockIdx.x; } else { a = a1; blk = blockIdx.x - B0; }
    int dst = blk * 4 + (threadIdx.x >> 6);
    if (dst >= a.N) return;
    int lane = threadIdx.x & 63;

    unsigned qp = a.q[(size_t)dst * 64 + lane];
    float qlo = bflo(qp), qhi = bfhi(qp);
    int beg = a.row_ptr[dst], end = a.row_ptr[dst + 1];
    float denl = 0.f, denh = 0.f, accl = 0.f, acch = 0.f;

    // prologue: load pair (beg, beg+1). srcs padded with 0 past E (node 0 = finite
    // data); e over-reads past E land in the adjacent buffer (finite data/zeros by
    // layout). Invalid second-edge contributions are masked to 0 after exp.
    int s0 = a.srcs[beg], s1 = a.srcs[beg + 1];
    unsigned k0 = a.kv[(size_t)s0 * 128 + lane];
    unsigned v0 = a.kv[(size_t)s0 * 128 + 64 + lane];
    unsigned e0 = a.e[(size_t)beg * 64 + lane];
    unsigned k1 = a.kv[(size_t)s1 * 128 + lane];
    unsigned v1 = a.kv[(size_t)s1 * 128 + 64 + lane];
    unsigned e1 = a.e[(size_t)(beg + 1) * 64 + lane];

    for (int i = beg; i < end; i += 2) {
        // prefetch next pair (always safe due to padding/adjacent finite data)
        int sn0 = a.srcs[i + 2], sn1 = a.srcs[i + 3];
        unsigned kn0 = a.kv[(size_t)sn0 * 128 + lane];
        unsigned vn0 = a.kv[(size_t)sn0 * 128 + 64 + lane];
        unsigned en0 = a.e[(size_t)(i + 2) * 64 + lane];
        unsigned kn1 = a.kv[(size_t)sn1 * 128 + lane];
        unsigned vn1 = a.kv[(size_t)sn1 * 128 + 64 + lane];
        unsigned en1 = a.e[(size_t)(i + 3) * 64 + lane];

        float e0l = bflo(e0), e0h = bfhi(e0);
        float e1l = bflo(e1), e1h = bfhi(e1);
        float p0l = qlo * (bflo(k0) + e0l), p0h = qhi * (bfhi(k0) + e0h);
        float p1l = qlo * (bflo(k1) + e1l), p1h = qhi * (bfhi(k1) + e1h);
        // 4 independent 16-lane reduction trees (ILP = 4)
#pragma unroll
        for (int m = 1; m < 16; m <<= 1) {
            p0l += __shfl_xor(p0l, m, 64);
            p0h += __shfl_xor(p0h, m, 64);
            p1l += __shfl_xor(p1l, m, 64);
            p1h += __shfl_xor(p1h, m, 64);
        }
        float x0l = __expf(p0l * 0.25f), x0h = __expf(p0h * 0.25f);
        float x1l = __expf(p1l * 0.25f), x1h = __expf(p1h * 0.25f);
        bool second = (i + 1 < end);
        x1l = second ? x1l : 0.f;
        x1h = second ? x1h : 0.f;
        denl += x0l + x1l;
        denh += x0h + x1h;
        accl += x0l * (bflo(v0) + e0l) + x1l * (bflo(v1) + e1l);
        acch += x0h * (bfhi(v0) + e0h) + x1h * (bfhi(v1) + e1h);
        k0 = kn0; v0 = vn0; e0 = en0;
        k1 = kn1; v1 = vn1; e1 = en1;
    }
    float ol = denl > 0.f ? accl / denl : 0.f;
    float oh = denh > 0.f ? acch / denh : 0.f;
    a.agg[(size_t)dst * 64 + lane] = (unsigned)f2bf(ol) | ((unsigned)f2bf(oh) << 16);
}

extern "C" void kernel_launch(void* const* d_in, const int* in_sizes, int n_in,
                              void* d_out, int out_size, void* d_ws, size_t ws_size,
                              hipStream_t stream) {
    const float* x_pc  = (const float*)d_in[0];
    const float* x_gr  = (const float*)d_in[1];
    const float* ea_pp = (const float*)d_in[2];
    const float* ea_pg = (const float*)d_in[3];
    const int* ei_pp   = (const int*)d_in[4];
    const int* ei_pg   = (const int*)d_in[5];
    const float *Wq_pp = (const float*)d_in[6],  *bq_pp = (const float*)d_in[7];
    const float *Wk_pp = (const float*)d_in[8],  *bk_pp = (const float*)d_in[9];
    const float *Wv_pp = (const float*)d_in[10], *bv_pp = (const float*)d_in[11];
    const float *We_pp = (const float*)d_in[12], *be_pp = (const float*)d_in[13];
    const float *Wo_pp = (const float*)d_in[14], *bo_pp = (const float*)d_in[15];
    const float *Wq_pg = (const float*)d_in[16], *bq_pg = (const float*)d_in[17];
    const float *Wk_pg = (const float*)d_in[18], *bk_pg = (const float*)d_in[19];
    const float *Wv_pg = (const float*)d_in[20], *bv_pg = (const float*)d_in[21];
    const float *We_pg = (const float*)d_in[22], *be_pg = (const float*)d_in[23];
    const float *Wo_pg = (const float*)d_in[24], *bo_pg = (const float*)d_in[25];
    const float *Wnp_pc = (const float*)d_in[26], *bnp_pc = (const float*)d_in[27];
    const float *g_pc   = (const float*)d_in[28], *bln_pc = (const float*)d_in[29];
    const float *Wnp_gr = (const float*)d_in[30], *bnp_gr = (const float*)d_in[31];
    const float *g_gr   = (const float*)d_in[32], *bln_gr = (const float*)d_in[33];

    const int N_pc = in_sizes[0] / 128;
    const int N_gr = in_sizes[1] / 128;
    const int E_pp = in_sizes[4] / 2;
    const int E_pg = in_sizes[5] / 2;

    char* ws = (char*)d_ws;
    size_t off = 0;
    auto alloc = [&](size_t bytes) -> char* {
        char* p = ws + off;
        off += (bytes + 255) & ~(size_t)255;
        return p;
    };
    unsigned short* Wt_q_pp = (unsigned short*)alloc(128 * 128 * 2);
    unsigned short* Wt_k_pp = (unsigned short*)alloc(128 * 128 * 2);
    unsigned short* Wt_v_pp = (unsigned short*)alloc(128 * 128 * 2);
    unsigned short* Wt_k_pg = (unsigned short*)alloc(128 * 128 * 2);
    unsigned short* Wt_v_pg = (unsigned short*)alloc(128 * 128 * 2);
    unsigned short* Wt_q_pg = (unsigned short*)alloc(128 * 128 * 2);
    unsigned short* Wt_e_pp = (unsigned short*)alloc(64 * 128 * 2);
    unsigned short* Wt_e_pg = (unsigned short*)alloc(64 * 128 * 2);
    unsigned short* Wt_cat_pp = (unsigned short*)alloc(256 * 128 * 2);
    unsigned short* Wt_cat_gr = (unsigned short*)alloc(256 * 128 * 2);

    unsigned int* q_pp  = (unsigned int*)alloc((size_t)N_pc * 64 * 4);
    unsigned int* kv_pp = (unsigned int*)alloc((size_t)N_pc * 128 * 4);
    unsigned int* q_pg  = (unsigned int*)alloc((size_t)N_gr * 64 * 4);
    unsigned int* kv_pg = (unsigned int*)alloc((size_t)N_pc * 128 * 4);
    unsigned int* agg_pp = (unsigned int*)alloc((size_t)N_pc * 64 * 4);
    unsigned int* agg_pg = (unsigned int*)alloc((size_t)N_gr * 64 * 4);
    int* row_ptr_pp = (int*)alloc((size_t)(N_pc + 1) * 4);
    int* cursor_pp  = (int*)alloc((size_t)N_pc * 4);
    int* pos_pp     = (int*)alloc((size_t)E_pp * 4);
    int* row_ptr_pg = (int*)alloc((size_t)(N_gr + 1) * 4);
    int* cursor_pg  = (int*)alloc((size_t)N_gr * 4);
    int* pos_pg     = (int*)alloc((size_t)E_pg * 4);
    int* bsum_pp    = (int*)alloc(64 * 4);
    int* boff_pp    = (int*)alloc(64 * 4);   // kept for layout stability (unused)
    int* bsum_pg    = (int*)alloc(64 * 4);
    int* boff_pg    = (int*)alloc(64 * 4);   // unused
    // e buffers: e_pp's 4-row over-read lands in e_pg (finite real data);
    // e_pg's 4-row over-read lands in the zeroed region below. Sizes are exact
    // multiples of 256 B so alloc() introduces no gaps.
    unsigned int* e_pp  = (unsigned int*)alloc((size_t)E_pp * 64 * 4);
    unsigned int* e_pg  = (unsigned int*)alloc((size_t)E_pg * 64 * 4);
    char* zbase = ws + off;   // zero region: counts + padded srcs (also e_pg spill)
    int* counts_pp = (int*)alloc((size_t)N_pc * 4);
    int* counts_pg = (int*)alloc((size_t)N_gr * 4);
    int* srcs_pp   = (int*)alloc((size_t)(E_pp + 8) * 4);  // pads stay zero
    int* srcs_pg   = (int*)alloc((size_t)(E_pg + 8) * 4);
    size_t zbytes = (size_t)((ws + off) - zbase);
    hipMemsetAsync(zbase, 0, zbytes, stream);

    float* out_pc = (float*)d_out;
    float* out_gr = out_pc + (size_t)N_pc * 128;

    const int* src_pp = ei_pp;
    const int* dst_pp = ei_pp + E_pp;
    const int* src_pg = ei_pg;
    const int* dst_pg = ei_pg + E_pg;

    // ---- weight prep + degree count (one launch) ----
    WPack wp;
    wp.w[0]  = {Wq_pp, Wt_q_pp, 128, 128, 0, 0};
    wp.w[1]  = {Wk_pp, Wt_k_pp, 128, 128, 0, 0};
    wp.w[2]  = {Wv_pp, Wt_v_pp, 128, 128, 0, 0};
    wp.w[3]  = {Wk_pg, Wt_k_pg, 128, 128, 0, 0};
    wp.w[4]  = {Wv_pg, Wt_v_pg, 128, 128, 0, 0};
    wp.w[5]  = {Wq_pg, Wt_q_pg, 128, 128, 0, 0};
    wp.w[6]  = {We_pp, Wt_e_pp, 64, 64, 0, 0};
    wp.w[7]  = {We_pg, Wt_e_pg, 64, 64, 0, 0};
    wp.w[8]  = {Wo_pp, Wt_cat_pp, 128, 256, 0, 1};    // paired-row perm (agg is paired)
    wp.w[9]  = {Wnp_pc, Wt_cat_pp, 128, 256, 128, 0};
    wp.w[10] = {Wo_pg, Wt_cat_gr, 128, 256, 0, 1};
    wp.w[11] = {Wnp_gr, Wt_cat_gr, 128, 256, 128, 0};
    const int NPREP = 48;
    const int gE = (E_pp + E_pg + 255) / 256;
    prep_and_count<<<NPREP + gE, 256, 0, stream>>>(wp, dst_pp, E_pp, counts_pp,
                                                   dst_pg, E_pg, counts_pg, NPREP);

    // ---- CSR build (3 launches instead of 4) ----
    const int Bs_pp = (N_pc + 1023) / 1024, Bs_pg = (N_gr + 1023) / 1024;
    scan_partial<<<Bs_pp + Bs_pg, 1024, 0, stream>>>(counts_pp, N_pc, row_ptr_pp, bsum_pp, Bs_pp,
                                                     counts_pg, N_gr, row_ptr_pg, bsum_pg);
    scan_midadd<<<Bs_pp + Bs_pg, 1024, 0, stream>>>(
        row_ptr_pp, cursor_pp, bsum_pp, N_pc, Bs_pp, &row_ptr_pp[N_pc],
        row_ptr_pg, cursor_pg, bsum_pg, N_gr, Bs_pg, &row_ptr_pg[N_gr]);
    scatter_both<<<gE, 256, 0, stream>>>(src_pp, dst_pp, E_pp, cursor_pp, pos_pp, srcs_pp,
                                         src_pg, dst_pg, E_pg, cursor_pg, pos_pg, srcs_pg);

    // ---- node projections (both node types, one launch) ----
    NodePack np;
    np.d[0] = {Wt_q_pp, bq_pp, q_pp, 64, 0};
    np.d[1] = {Wt_k_pp, bk_pp, kv_pp, 128, 0};
    np.d[2] = {Wt_v_pp, bv_pp, kv_pp, 128, 64};
    np.d[3] = {Wt_k_pg, bk_pg, kv_pg, 128, 0};
    np.d[4] = {Wt_v_pg, bv_pg, kv_pg, 128, 64};
    np.nout = 5;
    NodePack ng{};
    ng.d[0] = {Wt_q_pg, bq_pg, q_pg, 64, 0};
    ng.nout = 1;
    int Bn0 = (N_pc + 63) / 64, Bn1 = (N_gr + 63) / 64;
    gemm_node<<<Bn0 + Bn1, 256, 0, stream>>>(x_pc, N_pc, np, Bn0, x_gr, N_gr, ng);

    // ---- edge projections: wave-private tiles, barrier-free, CSR scatter ----
    EdgePack ep0 = {ea_pp, Wt_e_pp, be_pp, pos_pp, e_pp, E_pp};
    EdgePack ep1 = {ea_pg, Wt_e_pg, be_pg, pos_pg, e_pg, E_pg};
    int Be0 = (E_pp + 127) / 128, Be1 = (E_pg + 127) / 128;
    gemm_edge<<<Be0 + Be1, 256, 0, stream>>>(ep0, ep1, Be0);

    // ---- gather attention: 1 wave per dst, 2 edges per iteration ----
    AttnPack ap0 = {q_pp, kv_pp, e_pp, srcs_pp, row_ptr_pp, agg_pp, N_pc};
    AttnPack ap1 = {q_pg, kv_pg, e_pg, srcs_pg, row_ptr_pg, agg_pg, N_gr};
    int Ba0 = (N_pc + 3) / 4, Ba1 = (N_gr + 3) / 4;
    attn_gather<<<Ba0 + Ba1, 256, 0, stream>>>(ap0, ap1, Ba0);

    // ---- output GEMM + residual + LayerNorm ----
    OutPack op0 = {(const unsigned short*)agg_pp, x_pc, Wt_cat_pp, bo_pp, bnp_pc, g_pc, bln_pc, out_pc, N_pc};
    OutPack op1 = {(const unsigned short*)agg_pg, x_gr, Wt_cat_gr, bo_pg, bnp_gr, g_gr, bln_gr, out_gr, N_gr};
    int Bo0 = (N_pc + 63) / 64, Bo1 = (N_gr + 63) / 64;
    gemm_out_ln<<<Bo0 + Bo1, 256, 0, stream>>>(op0, op1, Bo0);
}